// Round 7
// baseline (27.159 us; speedup 1.0000x reference)
//
#include <hip/hip_runtime.h>

// Problem constants (from reference)
#define NRB 512
#define NTK 1024
#define DD  64
#define GHH 128

// Dead dataflow: tgt = edge_index[1]+512 in [512,1536) but robot_msgs =
// agg[:512] -> all-zero => edge MLP + segment_sum dead. lrelu(x) =
// 0.55x + 0.45|x| factors score into a[n] + c[m] + sum_h wb[h]*|HR+HTB|.
//
// R2: grid.sync ~60us -> kernel boundaries. R3: 256 VGPR -> latency-bound.
// R4: per-lane row reads uncoalesced -> HTBt transposed. R5: reg-array
// staging spills (133MB scratch). R6: score coalesced, 26us; remaining cost
// = prep's per-lane weight-ROW reads (64 lines/wave-instr, x3 phases, every
// block) and score's 3 uniform loads per h burning L1 port cycles.
// R7 fix: prep stages weights col-major in LDS (stride 129 -> 2-way free
// reads) from coalesced flat-f4 global loads; score stages hr/wb in LDS.

// Workspace layout (floats):
//   HR   [512][128]   @ 0        (row-major)
//   HTBt [128][1024]  @ 65536    (transposed, includes bm1)
//   a    [512]        @ 196608
//   c    [1024]       @ 197120
//   wb   [128]        @ 198144   (0.45 * Wm2)

// ---------------------------------------------------------------------------
// Kernel A: prep. 256 blocks x 256 threads.
// Blocks 0..127: robot path, 4 robots each -> HR rows, a[n].
// Blocks 128..255: task path, 8 tasks each -> HTBt cols, c[m]; block 128
// also writes wb. Weights staged col-major lds_w[k*129+i]: global read is
// coalesced flat float4; LDS read bank (k+i)%32 -> 2 lanes/bank (free).
// x / hidden activations read as LDS broadcasts (uniform addr, free).
// ---------------------------------------------------------------------------
__global__ __launch_bounds__(256) void prep_kernel(
    const float* __restrict__ xr, const float* __restrict__ xt,
    const float* __restrict__ Wv1, const float* __restrict__ bv1,
    const float* __restrict__ Wv2, const float* __restrict__ bv2,
    const float* __restrict__ Wm1, const float* __restrict__ bm1,
    const float* __restrict__ Wm2, const float* __restrict__ bm2,
    float* __restrict__ HR, float* __restrict__ HTBt,
    float* __restrict__ av, float* __restrict__ cv, float* __restrict__ wbv)
{
    const int t = threadIdx.x;   // 0..255
    const int b = blockIdx.x;    // 0..255
    const int i = t & 127;       // neuron
    const int g = t >> 7;        // row-group 0/1

    __shared__ float lds_w[128 * 129];   // 66048 B, col-major weights
    __shared__ float xs[8][64];          // input rows
    __shared__ float sA[4][128];         // h1 (robot)
    __shared__ float sB[4][128];         // h  (robot)
    __shared__ float sT[8][132];         // task pre-transpose
    __shared__ float sR[8][132];         // reduction scratch

    if (b < 128) {
        // ================= robot path: rows r0..r0+3 =================
        const int r0 = b * 4;
        ((float*)xs)[t] = xr[r0 * DD + t];           // 256 floats, coalesced

        // stage W1 = Wv1[:,128:192] -> lds_w[k*129+i]   (8192 floats)
        {
            const float4* W = reinterpret_cast<const float4*>(Wv1);
            #pragma unroll
            for (int j = 0; j < 8; ++j) {
                const int e   = t + 256 * j;          // f4 index 0..2047
                const int row = e >> 4, c4 = e & 15;
                float4 v = W[row * 48 + 32 + c4];     // coalesced
                const int k0 = c4 * 4;
                lds_w[(k0+0)*129 + row] = v.x;
                lds_w[(k0+1)*129 + row] = v.y;
                lds_w[(k0+2)*129 + row] = v.z;
                lds_w[(k0+3)*129 + row] = v.w;
            }
        }
        __syncthreads();

        // phase 1: h1 = lrelu(x @ W1^T + bv1), rows 2g, 2g+1
        {
            float a0 = bv1[i], a1 = a0;
            const float* x0 = xs[2*g];
            const float* x1 = xs[2*g + 1];
            #pragma unroll 8
            for (int k = 0; k < 64; ++k) {
                const float w = lds_w[k*129 + i];
                a0 = fmaf(w, x0[k], a0);
                a1 = fmaf(w, x1[k], a1);
            }
            sA[2*g][i]     = (a0 >= 0.f) ? a0 : 0.1f * a0;
            sA[2*g + 1][i] = (a1 >= 0.f) ? a1 : 0.1f * a1;
        }
        __syncthreads();

        // stage W2 = Wv2 [128][128]   (16384 floats)
        {
            const float4* W = reinterpret_cast<const float4*>(Wv2);
            #pragma unroll
            for (int j = 0; j < 16; ++j) {
                const int e   = t + 256 * j;          // 0..4095
                const int row = e >> 5, c4 = e & 31;
                float4 v = W[row * 32 + c4];
                const int k0 = c4 * 4;
                lds_w[(k0+0)*129 + row] = v.x;
                lds_w[(k0+1)*129 + row] = v.y;
                lds_w[(k0+2)*129 + row] = v.z;
                lds_w[(k0+3)*129 + row] = v.w;
            }
        }
        __syncthreads();

        // phase 2: h = h1 @ W2^T + bv2
        {
            float a0 = bv2[i], a1 = a0;
            const float* h0 = sA[2*g];
            const float* h1 = sA[2*g + 1];
            #pragma unroll 8
            for (int k = 0; k < 128; ++k) {
                const float w = lds_w[k*129 + i];
                a0 = fmaf(w, h0[k], a0);
                a1 = fmaf(w, h1[k], a1);
            }
            sB[2*g][i]     = a0;
            sB[2*g + 1][i] = a1;
        }
        __syncthreads();

        // stage W3 = Wm1[:, :128]   (16384 floats, row stride 192)
        {
            const float4* W = reinterpret_cast<const float4*>(Wm1);
            #pragma unroll
            for (int j = 0; j < 16; ++j) {
                const int e   = t + 256 * j;
                const int row = e >> 5, c4 = e & 31;
                float4 v = W[row * 48 + c4];
                const int k0 = c4 * 4;
                lds_w[(k0+0)*129 + row] = v.x;
                lds_w[(k0+1)*129 + row] = v.y;
                lds_w[(k0+2)*129 + row] = v.z;
                lds_w[(k0+3)*129 + row] = v.w;
            }
        }
        __syncthreads();

        // phase 3: hr = h @ W3^T; HR write + a-partials
        {
            const float wm2 = Wm2[i];
            float a0 = 0.f, a1 = 0.f;
            const float* h0 = sB[2*g];
            const float* h1 = sB[2*g + 1];
            #pragma unroll 8
            for (int k = 0; k < 128; ++k) {
                const float w = lds_w[k*129 + i];
                a0 = fmaf(w, h0[k], a0);
                a1 = fmaf(w, h1[k], a1);
            }
            HR[(r0 + 2*g) * GHH + i]     = a0;       // coalesced
            HR[(r0 + 2*g + 1) * GHH + i] = a1;
            sR[2*g][i]     = wm2 * a0;
            sR[2*g + 1][i] = wm2 * a1;
        }
        __syncthreads();

        // a[n] = 0.55 * sum_i sR[n][i];  one wave per row
        {
            const int row = t >> 6, c = t & 63;
            float s = sR[row][c] + sR[row][c + 64];
            #pragma unroll
            for (int off = 32; off >= 1; off >>= 1)
                s += __shfl_xor(s, off, 64);
            if (c == 0) av[r0 + row] = 0.55f * s;
        }
    } else {
        // ================= task path: tasks t0..t0+7 =================
        const int t0 = (b - 128) * 8;
        ((float*)xs)[t]       = xt[t0 * DD + t];
        ((float*)xs)[256 + t] = xt[t0 * DD + 256 + t];

        // stage Wt = Wm1[:,128:192] -> lds_w[k*129+i]   (8192 floats)
        {
            const float4* W = reinterpret_cast<const float4*>(Wm1);
            #pragma unroll
            for (int j = 0; j < 8; ++j) {
                const int e   = t + 256 * j;
                const int row = e >> 4, c4 = e & 15;
                float4 v = W[row * 48 + 32 + c4];
                const int k0 = c4 * 4;
                lds_w[(k0+0)*129 + row] = v.x;
                lds_w[(k0+1)*129 + row] = v.y;
                lds_w[(k0+2)*129 + row] = v.z;
                lds_w[(k0+3)*129 + row] = v.w;
            }
        }
        __syncthreads();

        // htb rows 4g..4g+3: htb = x_task @ Wt^T + bm1
        {
            const float bb  = bm1[i];
            const float wm2 = Wm2[i];
            float a0 = bb, a1 = bb, a2 = bb, a3 = bb;
            const float* x0 = xs[4*g];
            const float* x1 = xs[4*g + 1];
            const float* x2 = xs[4*g + 2];
            const float* x3 = xs[4*g + 3];
            #pragma unroll 8
            for (int k = 0; k < 64; ++k) {
                const float w = lds_w[k*129 + i];
                a0 = fmaf(w, x0[k], a0);
                a1 = fmaf(w, x1[k], a1);
                a2 = fmaf(w, x2[k], a2);
                a3 = fmaf(w, x3[k], a3);
            }
            sT[4*g][i]     = a0;  sR[4*g][i]     = wm2 * a0;
            sT[4*g + 1][i] = a1;  sR[4*g + 1][i] = wm2 * a1;
            sT[4*g + 2][i] = a2;  sR[4*g + 2][i] = wm2 * a2;
            sT[4*g + 3][i] = a3;  sR[4*g + 3][i] = wm2 * a3;
        }
        __syncthreads();

        // transposed write: HTBt[h][t0+tk]
        #pragma unroll
        for (int j = 0; j < 4; ++j) {
            const int e  = t + 256 * j;      // 0..1023
            const int h  = e >> 3, tk = e & 7;
            HTBt[h * NTK + t0 + tk] = sT[tk][h];
        }

        // c[m] = 0.55 * sum_i sR[m][i] + bm2;  half-wave per task
        {
            const int row = t >> 5, c = t & 31;
            float s = sR[row][c] + sR[row][c + 32]
                    + sR[row][c + 64] + sR[row][c + 96];
            #pragma unroll
            for (int off = 16; off >= 1; off >>= 1)
                s += __shfl_xor(s, off, 32);
            if (c == 0) cv[t0 + row] = 0.55f * s + bm2[0];
        }
        if (b == 128 && t < GHH) wbv[t] = 0.45f * Wm2[t];
    }
}

// ---------------------------------------------------------------------------
// Kernel B: fused score + softmax. 256 blocks x 1024 threads (4 waves/SIMD).
// Block b owns rows n0=2b,2b+1; thread tid owns column m=tid.
// hr0/hr1/wb staged in LDS (broadcast reads, no L1 port cost); per h just
// ONE coalesced dword load of HTBt[h][tid]. Then block softmax, coalesced
// store. No register arrays (R5 lesson).
// ---------------------------------------------------------------------------
__global__ __launch_bounds__(1024) void score_softmax_kernel(
    const float* __restrict__ HR, const float* __restrict__ HTBt,
    const float* __restrict__ av, const float* __restrict__ cv,
    const float* __restrict__ wbv, float* __restrict__ out)
{
    const int b   = blockIdx.x;     // 0..255
    const int tid = threadIdx.x;    // 0..1023 == m
    const int n0  = b * 2;

    __shared__ float s_hr[2 * GHH];   // rows n0, n0+1
    __shared__ float s_wb[GHH];
    if (tid < 256)      s_hr[tid]       = HR[n0 * GHH + tid];
    else if (tid < 384) s_wb[tid - 256] = wbv[tid - 256];
    __syncthreads();

    const float* tbp = HTBt + tid;
    float acc0 = 0.f, acc1 = 0.f;

    #pragma unroll 8
    for (int h = 0; h < 128; ++h) {
        const float tb = tbp[h * NTK];       // coalesced across lanes
        const float w  = s_wb[h];            // LDS broadcast
        acc0 = fmaf(w, fabsf(s_hr[h] + tb), acc0);
        acc1 = fmaf(w, fabsf(s_hr[GHH + h] + tb), acc1);
    }

    const float cm = cv[tid];
    float sc[2];
    sc[0] = acc0 + av[n0]     + cm;
    sc[1] = acc1 + av[n0 + 1] + cm;

    // ---- block-local softmax over the 1024 columns, both rows ----
    __shared__ float rmax[2][16], rsum[2][16];
    const int wid = tid >> 6, lane = tid & 63;

    #pragma unroll
    for (int n = 0; n < 2; ++n) {
        float mx = sc[n];
        #pragma unroll
        for (int off = 32; off >= 1; off >>= 1)
            mx = fmaxf(mx, __shfl_xor(mx, off, 64));
        if (lane == 0) rmax[n][wid] = mx;
    }
    __syncthreads();

    float ex[2];
    #pragma unroll
    for (int n = 0; n < 2; ++n) {
        float mx = rmax[n][0];
        #pragma unroll
        for (int k = 1; k < 16; ++k) mx = fmaxf(mx, rmax[n][k]);
        float e = expf(sc[n] - mx);
        ex[n] = e;
        float s = e;
        #pragma unroll
        for (int off = 32; off >= 1; off >>= 1) s += __shfl_xor(s, off, 64);
        if (lane == 0) rsum[n][wid] = s;
    }
    __syncthreads();

    #pragma unroll
    for (int n = 0; n < 2; ++n) {
        float s = rsum[n][0];
        #pragma unroll
        for (int k = 1; k < 16; ++k) s += rsum[n][k];
        out[(n0 + n) * NTK + tid] = ex[n] * (1.0f / s);
    }
}

extern "C" void kernel_launch(void* const* d_in, const int* in_sizes, int n_in,
                              void* d_out, int out_size, void* d_ws, size_t ws_size,
                              hipStream_t stream)
{
    const float* xr  = (const float*)d_in[0];
    const float* xt  = (const float*)d_in[1];
    // d_in[2]=edge_index, [3]=edge_attr, [4..7]=We1,be1,We2,be2 : provably dead
    const float* Wv1 = (const float*)d_in[8];
    const float* bv1 = (const float*)d_in[9];
    const float* Wv2 = (const float*)d_in[10];
    const float* bv2 = (const float*)d_in[11];
    const float* Wm1 = (const float*)d_in[12];
    const float* bm1 = (const float*)d_in[13];
    const float* Wm2 = (const float*)d_in[14];
    const float* bm2 = (const float*)d_in[15];

    float* ws   = (float*)d_ws;
    float* HR   = ws;
    float* HTBt = ws + 65536;
    float* av   = ws + 196608;
    float* cv   = ws + 197120;
    float* wbv  = ws + 198144;
    float* out  = (float*)d_out;

    hipLaunchKernelGGL(prep_kernel, dim3(256), dim3(256), 0, stream,
                       xr, xt, Wv1, bv1, Wv2, bv2, Wm1, bm1, Wm2, bm2,
                       HR, HTBt, av, cv, wbv);
    hipLaunchKernelGGL(score_softmax_kernel, dim3(256), dim3(1024), 0, stream,
                       HR, HTBt, av, cv, wbv, out);
}

// Round 8
// 25.750 us; speedup vs baseline: 1.0547x; 1.0547x over previous
//
#include <hip/hip_runtime.h>

// Problem constants (from reference)
#define NRB 512
#define NTK 1024
#define DD  64
#define GHH 128

// Dead dataflow: tgt = edge_index[1]+512 in [512,1536) but robot_msgs =
// agg[:512] -> all-zero => edge MLP + segment_sum dead. lrelu(x) =
// 0.55x + 0.45|x| factors score into a[n] + c[m] + sum_h wb[h]*|HR+HTB|.
//
// R2: grid.sync ~60us -> kernel boundaries. R3: 256 VGPR -> latency-bound.
// R4: per-lane row reads uncoalesced -> transpose. R5: reg-array staging
// spills. R6/R7: coalesced dword stream, 26-27us; prep rework neutral =>
// score + fixed cost dominate; score loop is ISSUE-bound (1 vmem + 3 LDS +
// 6 VALU per h). R8: pack 4 h per float4 -> HTBt4[h4][m][4]; score does
// 32 iters of {1 dwordx4 + 3 uniform b128 + 16 VALU} (~3x fewer issues).

// Workspace layout (floats):
//   HR    [512][128]     @ 0        (row-major)
//   HTBt4 [32][1024][4]  @ 65536    (h-interleaved transpose, incl bm1)
//   a     [512]          @ 196608
//   c     [1024]         @ 197120
//   wb    [128]          @ 198144   (0.45 * Wm2)

// ---------------------------------------------------------------------------
// Kernel A: prep. 256 blocks x 256 threads (same as R7 except HTBt4 write).
// Blocks 0..127: robot path, 4 robots each -> HR rows, a[n].
// Blocks 128..255: task path, 8 tasks each -> HTBt4, c[m]; block 128 wb.
// ---------------------------------------------------------------------------
__global__ __launch_bounds__(256) void prep_kernel(
    const float* __restrict__ xr, const float* __restrict__ xt,
    const float* __restrict__ Wv1, const float* __restrict__ bv1,
    const float* __restrict__ Wv2, const float* __restrict__ bv2,
    const float* __restrict__ Wm1, const float* __restrict__ bm1,
    const float* __restrict__ Wm2, const float* __restrict__ bm2,
    float* __restrict__ HR, float* __restrict__ HTBt4,
    float* __restrict__ av, float* __restrict__ cv, float* __restrict__ wbv)
{
    const int t = threadIdx.x;   // 0..255
    const int b = blockIdx.x;    // 0..255
    const int i = t & 127;       // neuron
    const int g = t >> 7;        // row-group 0/1

    __shared__ float lds_w[128 * 129];   // 66048 B, col-major weights
    __shared__ float xs[8][64];          // input rows
    __shared__ float sA[4][128];         // h1 (robot)
    __shared__ float sB[4][128];         // h  (robot)
    __shared__ float sT[8][132];         // task pre-transpose
    __shared__ float sR[8][132];         // reduction scratch

    if (b < 128) {
        // ================= robot path: rows r0..r0+3 =================
        const int r0 = b * 4;
        ((float*)xs)[t] = xr[r0 * DD + t];           // 256 floats, coalesced

        // stage W1 = Wv1[:,128:192] -> lds_w[k*129+i]   (8192 floats)
        {
            const float4* W = reinterpret_cast<const float4*>(Wv1);
            #pragma unroll
            for (int j = 0; j < 8; ++j) {
                const int e   = t + 256 * j;          // f4 index 0..2047
                const int row = e >> 4, c4 = e & 15;
                float4 v = W[row * 48 + 32 + c4];     // coalesced
                const int k0 = c4 * 4;
                lds_w[(k0+0)*129 + row] = v.x;
                lds_w[(k0+1)*129 + row] = v.y;
                lds_w[(k0+2)*129 + row] = v.z;
                lds_w[(k0+3)*129 + row] = v.w;
            }
        }
        __syncthreads();

        // phase 1: h1 = lrelu(x @ W1^T + bv1), rows 2g, 2g+1
        {
            float a0 = bv1[i], a1 = a0;
            const float* x0 = xs[2*g];
            const float* x1 = xs[2*g + 1];
            #pragma unroll 8
            for (int k = 0; k < 64; ++k) {
                const float w = lds_w[k*129 + i];
                a0 = fmaf(w, x0[k], a0);
                a1 = fmaf(w, x1[k], a1);
            }
            sA[2*g][i]     = (a0 >= 0.f) ? a0 : 0.1f * a0;
            sA[2*g + 1][i] = (a1 >= 0.f) ? a1 : 0.1f * a1;
        }
        __syncthreads();

        // stage W2 = Wv2 [128][128]   (16384 floats)
        {
            const float4* W = reinterpret_cast<const float4*>(Wv2);
            #pragma unroll
            for (int j = 0; j < 16; ++j) {
                const int e   = t + 256 * j;          // 0..4095
                const int row = e >> 5, c4 = e & 31;
                float4 v = W[row * 32 + c4];
                const int k0 = c4 * 4;
                lds_w[(k0+0)*129 + row] = v.x;
                lds_w[(k0+1)*129 + row] = v.y;
                lds_w[(k0+2)*129 + row] = v.z;
                lds_w[(k0+3)*129 + row] = v.w;
            }
        }
        __syncthreads();

        // phase 2: h = h1 @ W2^T + bv2
        {
            float a0 = bv2[i], a1 = a0;
            const float* h0 = sA[2*g];
            const float* h1 = sA[2*g + 1];
            #pragma unroll 8
            for (int k = 0; k < 128; ++k) {
                const float w = lds_w[k*129 + i];
                a0 = fmaf(w, h0[k], a0);
                a1 = fmaf(w, h1[k], a1);
            }
            sB[2*g][i]     = a0;
            sB[2*g + 1][i] = a1;
        }
        __syncthreads();

        // stage W3 = Wm1[:, :128]   (16384 floats, row stride 192)
        {
            const float4* W = reinterpret_cast<const float4*>(Wm1);
            #pragma unroll
            for (int j = 0; j < 16; ++j) {
                const int e   = t + 256 * j;
                const int row = e >> 5, c4 = e & 31;
                float4 v = W[row * 48 + c4];
                const int k0 = c4 * 4;
                lds_w[(k0+0)*129 + row] = v.x;
                lds_w[(k0+1)*129 + row] = v.y;
                lds_w[(k0+2)*129 + row] = v.z;
                lds_w[(k0+3)*129 + row] = v.w;
            }
        }
        __syncthreads();

        // phase 3: hr = h @ W3^T; HR write + a-partials
        {
            const float wm2 = Wm2[i];
            float a0 = 0.f, a1 = 0.f;
            const float* h0 = sB[2*g];
            const float* h1 = sB[2*g + 1];
            #pragma unroll 8
            for (int k = 0; k < 128; ++k) {
                const float w = lds_w[k*129 + i];
                a0 = fmaf(w, h0[k], a0);
                a1 = fmaf(w, h1[k], a1);
            }
            HR[(r0 + 2*g) * GHH + i]     = a0;       // coalesced
            HR[(r0 + 2*g + 1) * GHH + i] = a1;
            sR[2*g][i]     = wm2 * a0;
            sR[2*g + 1][i] = wm2 * a1;
        }
        __syncthreads();

        // a[n] = 0.55 * sum_i sR[n][i];  one wave per row
        {
            const int row = t >> 6, c = t & 63;
            float s = sR[row][c] + sR[row][c + 64];
            #pragma unroll
            for (int off = 32; off >= 1; off >>= 1)
                s += __shfl_xor(s, off, 64);
            if (c == 0) av[r0 + row] = 0.55f * s;
        }
    } else {
        // ================= task path: tasks t0..t0+7 =================
        const int t0 = (b - 128) * 8;
        ((float*)xs)[t]       = xt[t0 * DD + t];
        ((float*)xs)[256 + t] = xt[t0 * DD + 256 + t];

        // stage Wt = Wm1[:,128:192] -> lds_w[k*129+i]   (8192 floats)
        {
            const float4* W = reinterpret_cast<const float4*>(Wm1);
            #pragma unroll
            for (int j = 0; j < 8; ++j) {
                const int e   = t + 256 * j;
                const int row = e >> 4, c4 = e & 15;
                float4 v = W[row * 48 + 32 + c4];
                const int k0 = c4 * 4;
                lds_w[(k0+0)*129 + row] = v.x;
                lds_w[(k0+1)*129 + row] = v.y;
                lds_w[(k0+2)*129 + row] = v.z;
                lds_w[(k0+3)*129 + row] = v.w;
            }
        }
        __syncthreads();

        // htb rows 4g..4g+3: htb = x_task @ Wt^T + bm1
        {
            const float bb  = bm1[i];
            const float wm2 = Wm2[i];
            float a0 = bb, a1 = bb, a2 = bb, a3 = bb;
            const float* x0 = xs[4*g];
            const float* x1 = xs[4*g + 1];
            const float* x2 = xs[4*g + 2];
            const float* x3 = xs[4*g + 3];
            #pragma unroll 8
            for (int k = 0; k < 64; ++k) {
                const float w = lds_w[k*129 + i];
                a0 = fmaf(w, x0[k], a0);
                a1 = fmaf(w, x1[k], a1);
                a2 = fmaf(w, x2[k], a2);
                a3 = fmaf(w, x3[k], a3);
            }
            sT[4*g][i]     = a0;  sR[4*g][i]     = wm2 * a0;
            sT[4*g + 1][i] = a1;  sR[4*g + 1][i] = wm2 * a1;
            sT[4*g + 2][i] = a2;  sR[4*g + 2][i] = wm2 * a2;
            sT[4*g + 3][i] = a3;  sR[4*g + 3][i] = wm2 * a3;
        }
        __syncthreads();

        // interleaved transposed write: HTBt4[h4][t0+tk][j] = htb[tk][4h4+j]
        // thread t -> (h4 = t>>3, tk = t&7): one float4 store, coalesced.
        {
            const int h4 = t >> 3, tk = t & 7;
            float4 v;
            v.x = sT[tk][4*h4 + 0];
            v.y = sT[tk][4*h4 + 1];
            v.z = sT[tk][4*h4 + 2];
            v.w = sT[tk][4*h4 + 3];
            reinterpret_cast<float4*>(HTBt4)[h4 * NTK + t0 + tk] = v;
        }

        // c[m] = 0.55 * sum_i sR[m][i] + bm2;  half-wave per task
        {
            const int row = t >> 5, c = t & 31;
            float s = sR[row][c] + sR[row][c + 32]
                    + sR[row][c + 64] + sR[row][c + 96];
            #pragma unroll
            for (int off = 16; off >= 1; off >>= 1)
                s += __shfl_xor(s, off, 32);
            if (c == 0) cv[t0 + row] = 0.55f * s + bm2[0];
        }
        if (b == 128 && t < GHH) wbv[t] = 0.45f * Wm2[t];
    }
}

// ---------------------------------------------------------------------------
// Kernel B: fused score + softmax. 256 blocks x 1024 threads (4 waves/SIMD).
// Block b owns rows n0=2b,2b+1; thread tid owns column m=tid.
// Per h4 (32 iters): ONE global_load_dwordx4 of HTBt4[h4][tid] (coalesced,
// 16B/lane) + 3 uniform ds_read_b128 (wb4 / hr0_4 / hr1_4) + 16 VALU.
// ~3x fewer issue slots than the per-h dword loop (R8 theory). Then block
// softmax, coalesced store. No register arrays (R5 lesson).
// ---------------------------------------------------------------------------
__global__ __launch_bounds__(1024) void score_softmax_kernel(
    const float* __restrict__ HR, const float* __restrict__ HTBt4,
    const float* __restrict__ av, const float* __restrict__ cv,
    const float* __restrict__ wbv, float* __restrict__ out)
{
    const int b   = blockIdx.x;     // 0..255
    const int tid = threadIdx.x;    // 0..1023 == m
    const int n0  = b * 2;

    __shared__ float s_hr[2 * GHH];   // rows n0, n0+1 (256 floats)
    __shared__ float s_wb[GHH];
    if (tid < 256)      s_hr[tid]       = HR[n0 * GHH + tid];
    else if (tid < 384) s_wb[tid - 256] = wbv[tid - 256];
    __syncthreads();

    const float4* tb  = reinterpret_cast<const float4*>(HTBt4) + tid;
    const float4* hrA = reinterpret_cast<const float4*>(s_hr);
    const float4* hrB = reinterpret_cast<const float4*>(s_hr + GHH);
    const float4* wb4 = reinterpret_cast<const float4*>(s_wb);

    float acc0 = 0.f, acc1 = 0.f;

    #pragma unroll 4
    for (int h4 = 0; h4 < 32; ++h4) {
        const float4 v  = tb[h4 << 10];     // coalesced dwordx4
        const float4 w  = wb4[h4];          // uniform b128 broadcasts
        const float4 r0 = hrA[h4];
        const float4 r1 = hrB[h4];
        acc0 = fmaf(w.x, fabsf(r0.x + v.x), acc0);
        acc1 = fmaf(w.x, fabsf(r1.x + v.x), acc1);
        acc0 = fmaf(w.y, fabsf(r0.y + v.y), acc0);
        acc1 = fmaf(w.y, fabsf(r1.y + v.y), acc1);
        acc0 = fmaf(w.z, fabsf(r0.z + v.z), acc0);
        acc1 = fmaf(w.z, fabsf(r1.z + v.z), acc1);
        acc0 = fmaf(w.w, fabsf(r0.w + v.w), acc0);
        acc1 = fmaf(w.w, fabsf(r1.w + v.w), acc1);
    }

    const float cm = cv[tid];
    float sc[2];
    sc[0] = acc0 + av[n0]     + cm;
    sc[1] = acc1 + av[n0 + 1] + cm;

    // ---- block-local softmax over the 1024 columns, both rows ----
    __shared__ float rmax[2][16], rsum[2][16];
    const int wid = tid >> 6, lane = tid & 63;

    #pragma unroll
    for (int n = 0; n < 2; ++n) {
        float mx = sc[n];
        #pragma unroll
        for (int off = 32; off >= 1; off >>= 1)
            mx = fmaxf(mx, __shfl_xor(mx, off, 64));
        if (lane == 0) rmax[n][wid] = mx;
    }
    __syncthreads();

    float ex[2];
    #pragma unroll
    for (int n = 0; n < 2; ++n) {
        float mx = rmax[n][0];
        #pragma unroll
        for (int k = 1; k < 16; ++k) mx = fmaxf(mx, rmax[n][k]);
        float e = expf(sc[n] - mx);
        ex[n] = e;
        float s = e;
        #pragma unroll
        for (int off = 32; off >= 1; off >>= 1) s += __shfl_xor(s, off, 64);
        if (lane == 0) rsum[n][wid] = s;
    }
    __syncthreads();

    #pragma unroll
    for (int n = 0; n < 2; ++n) {
        float s = rsum[n][0];
        #pragma unroll
        for (int k = 1; k < 16; ++k) s += rsum[n][k];
        out[(n0 + n) * NTK + tid] = ex[n] * (1.0f / s);
    }
}

extern "C" void kernel_launch(void* const* d_in, const int* in_sizes, int n_in,
                              void* d_out, int out_size, void* d_ws, size_t ws_size,
                              hipStream_t stream)
{
    const float* xr  = (const float*)d_in[0];
    const float* xt  = (const float*)d_in[1];
    // d_in[2]=edge_index, [3]=edge_attr, [4..7]=We1,be1,We2,be2 : provably dead
    const float* Wv1 = (const float*)d_in[8];
    const float* bv1 = (const float*)d_in[9];
    const float* Wv2 = (const float*)d_in[10];
    const float* bv2 = (const float*)d_in[11];
    const float* Wm1 = (const float*)d_in[12];
    const float* bm1 = (const float*)d_in[13];
    const float* Wm2 = (const float*)d_in[14];
    const float* bm2 = (const float*)d_in[15];

    float* ws    = (float*)d_ws;
    float* HR    = ws;
    float* HTBt4 = ws + 65536;
    float* av    = ws + 196608;
    float* cv    = ws + 197120;
    float* wbv   = ws + 198144;
    float* out   = (float*)d_out;

    hipLaunchKernelGGL(prep_kernel, dim3(256), dim3(256), 0, stream,
                       xr, xt, Wv1, bv1, Wv2, bv2, Wm1, bm1, Wm2, bm2,
                       HR, HTBt4, av, cv, wbv);
    hipLaunchKernelGGL(score_softmax_kernel, dim3(256), dim3(1024), 0, stream,
                       HR, HTBt4, av, cv, wbv, out);
}

// Round 9
// 22.578 us; speedup vs baseline: 1.2029x; 1.1405x over previous
//
#include <hip/hip_runtime.h>

// Problem constants (from reference)
#define NRB 512
#define NTK 1024
#define DD  64
#define GHH 128

// Dead dataflow: tgt = edge_index[1]+512 in [512,1536) but robot_msgs =
// agg[:512] -> all-zero => edge MLP + segment_sum dead. lrelu(x) =
// 0.55x + 0.45|x| factors score into a[n] + c[m] + sum_h wb[h]*|HR+HTB|.
//
// R2: grid.sync ~60us -> kernel boundaries. R3: 256 VGPR -> latency-bound.
// R4: uncoalesced row reads -> transpose. R5: reg-array staging spills.
// R6-R8: score rewrites ~neutral => PREP dominates (~11us): its loops were
// 3 LDS-b32 per 2 FMA. R9: all-b128 prep (w row-major stride-132 -> b128
// lane reads start bank 4i%32; staging 1 f4 load -> 1 f4 store; x/h
// broadcasts as f4) = 3 LDS per 8 FMA; score drops LDS staging, reads
// wb/hr as uniform global f4 (s_load candidates), zero LDS in main loop.

// Workspace layout (floats):
//   HR    [512][128]     @ 0        (row-major)
//   HTBt4 [32][1024][4]  @ 65536    (h-interleaved transpose, incl bm1)
//   a     [512]          @ 196608
//   c     [1024]         @ 197120
//   wb    [128]          @ 198144   (0.45 * Wm2)

// ---------------------------------------------------------------------------
// Kernel A: prep. 256 blocks x 256 threads.
// Blocks 0..127: robot path, 4 robots -> HR rows + a[n].
// Blocks 128..255: task path, 8 tasks -> HTBt4 + c[m]; block 128 wb.
// lds_w[i][132] row-major: col-i b128 read = banks 4i%32..+3 (optimal);
// staged via coalesced global f4 -> single LDS f4 store.
// ---------------------------------------------------------------------------
__global__ __launch_bounds__(256) void prep_kernel(
    const float* __restrict__ xr, const float* __restrict__ xt,
    const float* __restrict__ Wv1, const float* __restrict__ bv1,
    const float* __restrict__ Wv2, const float* __restrict__ bv2,
    const float* __restrict__ Wm1, const float* __restrict__ bm1,
    const float* __restrict__ Wm2, const float* __restrict__ bm2,
    float* __restrict__ HR, float* __restrict__ HTBt4,
    float* __restrict__ av, float* __restrict__ cv, float* __restrict__ wbv)
{
    const int t = threadIdx.x;   // 0..255
    const int b = blockIdx.x;    // 0..255
    const int i = t & 127;       // output neuron (column)
    const int g = t >> 7;        // row-group 0/1

    __shared__ float lds_w[128 * 132];   // row-major weights, stride 132
    __shared__ float xs[8 * 64];         // input rows (flat)
    __shared__ float sA[4 * 132];        // h1 (robot)
    __shared__ float sB[4 * 132];        // h  (robot)
    __shared__ float sT[8 * 132];        // task pre-transpose
    __shared__ float sR[8 * 132];        // reduction scratch

    float4* Lw = reinterpret_cast<float4*>(lds_w);

    if (b < 128) {
        // ================= robot path: rows r0..r0+3 =================
        const int r0 = b * 4;
        xs[t] = xr[r0 * DD + t];                     // 256 floats, coalesced

        // stage W1 = Wv1[:,128:192]: 2048 f4, 1 load + 1 store each
        {
            const float4* W = reinterpret_cast<const float4*>(Wv1);
            #pragma unroll
            for (int j = 0; j < 8; ++j) {
                const int e = t + 256 * j;           // 0..2047
                const int row = e >> 4, c4 = e & 15;
                Lw[row * 33 + c4] = W[row * 48 + 32 + c4];
            }
        }
        __syncthreads();

        // phase 1: h1 = lrelu(x @ W1^T + bv1), rows 2g,2g+1, col i
        {
            float a0 = bv1[i], a1 = a0;
            const float4* w4 = Lw + i * 33;
            const float4* x0 = reinterpret_cast<const float4*>(xs + (2*g)*64);
            const float4* x1 = reinterpret_cast<const float4*>(xs + (2*g+1)*64);
            #pragma unroll
            for (int k = 0; k < 16; ++k) {
                const float4 w = w4[k];
                const float4 p = x0[k];
                const float4 q = x1[k];
                a0 = fmaf(w.x, p.x, a0); a1 = fmaf(w.x, q.x, a1);
                a0 = fmaf(w.y, p.y, a0); a1 = fmaf(w.y, q.y, a1);
                a0 = fmaf(w.z, p.z, a0); a1 = fmaf(w.z, q.z, a1);
                a0 = fmaf(w.w, p.w, a0); a1 = fmaf(w.w, q.w, a1);
            }
            sA[(2*g)*132 + i]   = (a0 >= 0.f) ? a0 : 0.1f * a0;
            sA[(2*g+1)*132 + i] = (a1 >= 0.f) ? a1 : 0.1f * a1;
        }
        __syncthreads();

        // stage W2 = Wv2 [128][128]: 4096 f4
        {
            const float4* W = reinterpret_cast<const float4*>(Wv2);
            #pragma unroll
            for (int j = 0; j < 16; ++j) {
                const int e = t + 256 * j;           // 0..4095
                const int row = e >> 5, c4 = e & 31;
                Lw[row * 33 + c4] = W[row * 32 + c4];
            }
        }
        __syncthreads();

        // phase 2: h = h1 @ W2^T + bv2
        {
            float a0 = bv2[i], a1 = a0;
            const float4* w4 = Lw + i * 33;
            const float4* h0 = reinterpret_cast<const float4*>(sA + (2*g)*132);
            const float4* h1 = reinterpret_cast<const float4*>(sA + (2*g+1)*132);
            #pragma unroll 8
            for (int k = 0; k < 32; ++k) {
                const float4 w = w4[k];
                const float4 p = h0[k];
                const float4 q = h1[k];
                a0 = fmaf(w.x, p.x, a0); a1 = fmaf(w.x, q.x, a1);
                a0 = fmaf(w.y, p.y, a0); a1 = fmaf(w.y, q.y, a1);
                a0 = fmaf(w.z, p.z, a0); a1 = fmaf(w.z, q.z, a1);
                a0 = fmaf(w.w, p.w, a0); a1 = fmaf(w.w, q.w, a1);
            }
            sB[(2*g)*132 + i]   = a0;
            sB[(2*g+1)*132 + i] = a1;
        }
        __syncthreads();

        // stage W3 = Wm1[:, :128]: 4096 f4 (row stride 192 -> 48 f4)
        {
            const float4* W = reinterpret_cast<const float4*>(Wm1);
            #pragma unroll
            for (int j = 0; j < 16; ++j) {
                const int e = t + 256 * j;
                const int row = e >> 5, c4 = e & 31;
                Lw[row * 33 + c4] = W[row * 48 + c4];
            }
        }
        __syncthreads();

        // phase 3: hr = h @ W3^T; HR write + a-partials
        {
            const float wm2 = Wm2[i];
            float a0 = 0.f, a1 = 0.f;
            const float4* w4 = Lw + i * 33;
            const float4* h0 = reinterpret_cast<const float4*>(sB + (2*g)*132);
            const float4* h1 = reinterpret_cast<const float4*>(sB + (2*g+1)*132);
            #pragma unroll 8
            for (int k = 0; k < 32; ++k) {
                const float4 w = w4[k];
                const float4 p = h0[k];
                const float4 q = h1[k];
                a0 = fmaf(w.x, p.x, a0); a1 = fmaf(w.x, q.x, a1);
                a0 = fmaf(w.y, p.y, a0); a1 = fmaf(w.y, q.y, a1);
                a0 = fmaf(w.z, p.z, a0); a1 = fmaf(w.z, q.z, a1);
                a0 = fmaf(w.w, p.w, a0); a1 = fmaf(w.w, q.w, a1);
            }
            HR[(r0 + 2*g) * GHH + i]     = a0;       // coalesced
            HR[(r0 + 2*g + 1) * GHH + i] = a1;
            sR[(2*g)*132 + i]   = wm2 * a0;
            sR[(2*g+1)*132 + i] = wm2 * a1;
        }
        __syncthreads();

        // a[n] = 0.55 * sum_i sR[n][i];  one wave per row
        {
            const int row = t >> 6, c = t & 63;
            float s = sR[row*132 + c] + sR[row*132 + c + 64];
            #pragma unroll
            for (int off = 32; off >= 1; off >>= 1)
                s += __shfl_xor(s, off, 64);
            if (c == 0) av[r0 + row] = 0.55f * s;
        }
    } else {
        // ================= task path: tasks t0..t0+7 =================
        const int t0 = (b - 128) * 8;
        xs[t]       = xt[t0 * DD + t];
        xs[256 + t] = xt[t0 * DD + 256 + t];

        // stage Wt = Wm1[:,128:192]: 2048 f4
        {
            const float4* W = reinterpret_cast<const float4*>(Wm1);
            #pragma unroll
            for (int j = 0; j < 8; ++j) {
                const int e = t + 256 * j;
                const int row = e >> 4, c4 = e & 15;
                Lw[row * 33 + c4] = W[row * 48 + 32 + c4];
            }
        }
        __syncthreads();

        // rows 4g..4g+3: htb = x_task @ Wt^T + bm1
        {
            const float bb  = bm1[i];
            const float wm2 = Wm2[i];
            float a0 = bb, a1 = bb, a2 = bb, a3 = bb;
            const float4* w4 = Lw + i * 33;
            const float4* x0 = reinterpret_cast<const float4*>(xs + (4*g)*64);
            const float4* x1 = reinterpret_cast<const float4*>(xs + (4*g+1)*64);
            const float4* x2 = reinterpret_cast<const float4*>(xs + (4*g+2)*64);
            const float4* x3 = reinterpret_cast<const float4*>(xs + (4*g+3)*64);
            #pragma unroll
            for (int k = 0; k < 16; ++k) {
                const float4 w = w4[k];
                const float4 p0 = x0[k], p1 = x1[k], p2 = x2[k], p3 = x3[k];
                a0 = fmaf(w.x, p0.x, a0); a1 = fmaf(w.x, p1.x, a1);
                a2 = fmaf(w.x, p2.x, a2); a3 = fmaf(w.x, p3.x, a3);
                a0 = fmaf(w.y, p0.y, a0); a1 = fmaf(w.y, p1.y, a1);
                a2 = fmaf(w.y, p2.y, a2); a3 = fmaf(w.y, p3.y, a3);
                a0 = fmaf(w.z, p0.z, a0); a1 = fmaf(w.z, p1.z, a1);
                a2 = fmaf(w.z, p2.z, a2); a3 = fmaf(w.z, p3.z, a3);
                a0 = fmaf(w.w, p0.w, a0); a1 = fmaf(w.w, p1.w, a1);
                a2 = fmaf(w.w, p2.w, a2); a3 = fmaf(w.w, p3.w, a3);
            }
            sT[(4*g)*132 + i]   = a0;  sR[(4*g)*132 + i]   = wm2 * a0;
            sT[(4*g+1)*132 + i] = a1;  sR[(4*g+1)*132 + i] = wm2 * a1;
            sT[(4*g+2)*132 + i] = a2;  sR[(4*g+2)*132 + i] = wm2 * a2;
            sT[(4*g+3)*132 + i] = a3;  sR[(4*g+3)*132 + i] = wm2 * a3;
        }
        __syncthreads();

        // interleaved transposed write: HTBt4[h4][t0+tk] = htb[tk][4h4..4h4+3]
        {
            const int h4 = t >> 3, tk = t & 7;
            float4 v;
            v.x = sT[tk*132 + 4*h4 + 0];
            v.y = sT[tk*132 + 4*h4 + 1];
            v.z = sT[tk*132 + 4*h4 + 2];
            v.w = sT[tk*132 + 4*h4 + 3];
            reinterpret_cast<float4*>(HTBt4)[h4 * NTK + t0 + tk] = v;
        }

        // c[m] = 0.55 * sum_i sR[m][i] + bm2;  half-wave per task
        {
            const int row = t >> 5, c = t & 31;
            float s = sR[row*132 + c]      + sR[row*132 + c + 32]
                    + sR[row*132 + c + 64] + sR[row*132 + c + 96];
            #pragma unroll
            for (int off = 16; off >= 1; off >>= 1)
                s += __shfl_xor(s, off, 32);
            if (c == 0) cv[t0 + row] = 0.55f * s + bm2[0];
        }
        if (b == 128 && t < GHH) wbv[t] = 0.45f * Wm2[t];
    }
}

// ---------------------------------------------------------------------------
// Kernel B: fused score + softmax. 256 blocks x 1024 threads (4 waves/SIMD).
// Block b owns rows n0=2b,2b+1; thread tid owns column m=tid.
// Per h4 (32 iters): 1 coalesced dwordx4 of HTBt4[h4][tid] + 3 UNIFORM
// global f4 loads (wb4/hr0/hr1 -- same line per wave, s_load candidates,
// zero LDS) + 16 VALU. Then block softmax, coalesced store.
// ---------------------------------------------------------------------------
__global__ __launch_bounds__(1024) void score_softmax_kernel(
    const float* __restrict__ HR, const float* __restrict__ HTBt4,
    const float* __restrict__ av, const float* __restrict__ cv,
    const float* __restrict__ wbv, float* __restrict__ out)
{
    const int b   = blockIdx.x;     // 0..255
    const int tid = threadIdx.x;    // 0..1023 == m
    const int n0  = b * 2;

    const float4* tb  = reinterpret_cast<const float4*>(HTBt4) + tid;
    const float4* hrA = reinterpret_cast<const float4*>(HR + n0 * GHH);
    const float4* hrB = reinterpret_cast<const float4*>(HR + (n0 + 1) * GHH);
    const float4* wb4 = reinterpret_cast<const float4*>(wbv);

    float acc0 = 0.f, acc1 = 0.f;

    #pragma unroll 4
    for (int h4 = 0; h4 < 32; ++h4) {
        const float4 v  = tb[h4 << 10];     // coalesced dwordx4
        const float4 w  = wb4[h4];          // uniform
        const float4 r0 = hrA[h4];          // uniform
        const float4 r1 = hrB[h4];          // uniform
        acc0 = fmaf(w.x, fabsf(r0.x + v.x), acc0);
        acc1 = fmaf(w.x, fabsf(r1.x + v.x), acc1);
        acc0 = fmaf(w.y, fabsf(r0.y + v.y), acc0);
        acc1 = fmaf(w.y, fabsf(r1.y + v.y), acc1);
        acc0 = fmaf(w.z, fabsf(r0.z + v.z), acc0);
        acc1 = fmaf(w.z, fabsf(r1.z + v.z), acc1);
        acc0 = fmaf(w.w, fabsf(r0.w + v.w), acc0);
        acc1 = fmaf(w.w, fabsf(r1.w + v.w), acc1);
    }

    const float cm = cv[tid];
    float sc[2];
    sc[0] = acc0 + av[n0]     + cm;
    sc[1] = acc1 + av[n0 + 1] + cm;

    // ---- block-local softmax over the 1024 columns, both rows ----
    __shared__ float rmax[2][16], rsum[2][16];
    const int wid = tid >> 6, lane = tid & 63;

    #pragma unroll
    for (int n = 0; n < 2; ++n) {
        float mx = sc[n];
        #pragma unroll
        for (int off = 32; off >= 1; off >>= 1)
            mx = fmaxf(mx, __shfl_xor(mx, off, 64));
        if (lane == 0) rmax[n][wid] = mx;
    }
    __syncthreads();

    float ex[2];
    #pragma unroll
    for (int n = 0; n < 2; ++n) {
        float mx = rmax[n][0];
        #pragma unroll
        for (int k = 1; k < 16; ++k) mx = fmaxf(mx, rmax[n][k]);
        float e = expf(sc[n] - mx);
        ex[n] = e;
        float s = e;
        #pragma unroll
        for (int off = 32; off >= 1; off >>= 1) s += __shfl_xor(s, off, 64);
        if (lane == 0) rsum[n][wid] = s;
    }
    __syncthreads();

    #pragma unroll
    for (int n = 0; n < 2; ++n) {
        float s = rsum[n][0];
        #pragma unroll
        for (int k = 1; k < 16; ++k) s += rsum[n][k];
        out[(n0 + n) * NTK + tid] = ex[n] * (1.0f / s);
    }
}

extern "C" void kernel_launch(void* const* d_in, const int* in_sizes, int n_in,
                              void* d_out, int out_size, void* d_ws, size_t ws_size,
                              hipStream_t stream)
{
    const float* xr  = (const float*)d_in[0];
    const float* xt  = (const float*)d_in[1];
    // d_in[2]=edge_index, [3]=edge_attr, [4..7]=We1,be1,We2,be2 : provably dead
    const float* Wv1 = (const float*)d_in[8];
    const float* bv1 = (const float*)d_in[9];
    const float* Wv2 = (const float*)d_in[10];
    const float* bv2 = (const float*)d_in[11];
    const float* Wm1 = (const float*)d_in[12];
    const float* bm1 = (const float*)d_in[13];
    const float* Wm2 = (const float*)d_in[14];
    const float* bm2 = (const float*)d_in[15];

    float* ws    = (float*)d_ws;
    float* HR    = ws;
    float* HTBt4 = ws + 65536;
    float* av    = ws + 196608;
    float* cv    = ws + 197120;
    float* wbv   = ws + 198144;
    float* out   = (float*)d_out;

    hipLaunchKernelGGL(prep_kernel, dim3(256), dim3(256), 0, stream,
                       xr, xt, Wv1, bv1, Wv2, bv2, Wm1, bm1, Wm2, bm2,
                       HR, HTBt4, av, cv, wbv);
    hipLaunchKernelGGL(score_softmax_kernel, dim3(256), dim3(1024), 0, stream,
                       HR, HTBt4, av, cv, wbv, out);
}